// Round 9
// baseline (155.944 us; speedup 1.0000x reference)
//
#include <hip/hip_runtime.h>
#include <hip/hip_fp16.h>
#include <math.h>

#define SLOPE 0.01f
#define NLAYER 15
#define FINE_CELLS 512            // [-2, 2), h = 1/128
#define COARSE_CELLS 128          // [-32, 32), h = 1/2; extrapolate via clamped end cells
#define CELLS 640                 // per layer; cell = uint2: half2(s_m,s_v), half2(t_m,t_v)
#define FINE_NODES 513
#define NODES_PER_NET 642
#define TABLE_CELLS (NLAYER * CELLS)     // 9600 uint2 = 76800 B
#define INV_LN2 1.4426950408889634f
#define LN2F 0.6931471805599453f
#define TPB 512
#define CH 8                      // independent chains per thread iteration

__device__ __forceinline__ float fast_exp2(float x) {
#if __has_builtin(__builtin_amdgcn_exp2f)
    return __builtin_amdgcn_exp2f(x);
#else
    return __expf(x * LN2F);
#endif
}

// ---------------- exact scalar->32->16->1 MLP (precompute only) ----------------
__device__ __forceinline__ float mlp_exact(
    float x1,
    const float* __restrict__ W1, const float* __restrict__ b1,
    const float* __restrict__ W2, const float* __restrict__ b2,
    const float* __restrict__ W3, float b3)
{
    float h2[16];
#pragma unroll
    for (int n = 0; n < 16; ++n) h2[n] = b2[n];
#pragma unroll 2
    for (int j = 0; j < 32; ++j) {
        float h = fmaf(W1[j], x1, b1[j]);
        h = fmaxf(h, SLOPE * h);
#pragma unroll
        for (int n = 0; n < 16; ++n) h2[n] = fmaf(h, W2[j * 16 + n], h2[n]);
    }
    float o = b3;
#pragma unroll
    for (int n = 0; n < 16; ++n) {
        float h = fmaxf(h2[n], SLOPE * h2[n]);
        o = fmaf(h, W3[n], o);
    }
    return o;
}

// ---------------- build: one block per net (30 blocks) ----
// Cell stores CENTER-REFERENCED f16 (slope-per-index-step, center value):
//   val(u) = m*(u - i - 0.5) + v,  u = index-space coordinate, m = hi - lo.
// |du| <= 0.5 so f16 error hits v (rel 2^-11) and m*du (tiny).
// s-net values are in log2 units. (Format accuracy verified R7/R8: absmax 0.125.)
__global__ __launch_bounds__(640) void build_tables(
    const float* __restrict__ scale_w, const float* __restrict__ scale_b,
    const float* __restrict__ sW1, const float* __restrict__ sb1,
    const float* __restrict__ sW2, const float* __restrict__ sb2,
    const float* __restrict__ sW3, const float* __restrict__ sb3,
    const float* __restrict__ tW1, const float* __restrict__ tb1,
    const float* __restrict__ tW2, const float* __restrict__ tb2,
    const float* __restrict__ tW3, const float* __restrict__ tb3,
    float* __restrict__ ws)
{
    const int m = blockIdx.x;            // 0..29
    const int l = m >> 1;
    const int which = m & 1;             // 0 = s-net, 1 = t-net
    const float* W1 = (which ? tW1 : sW1) + l * 32;
    const float* b1 = (which ? tb1 : sb1) + l * 32;
    const float* W2 = (which ? tW2 : sW2) + l * 512;
    const float* b2 = (which ? tb2 : sb2) + l * 16;
    const float* W3 = (which ? tW3 : sW3) + l * 16;
    const float  b3 = which ? tb3[l] : sb3[l];

    __shared__ float nodes[NODES_PER_NET];

    for (int i = threadIdx.x; i < NODES_PER_NET; i += blockDim.x) {
        const float x = (i < FINE_NODES) ? (-2.0f + (float)i * (1.0f / 128.0f))
                                         : (-32.0f + (float)(i - FINE_NODES) * 0.5f);
        float o = mlp_exact(x, W1, b1, W2, b2, W3, b3);
        nodes[i] = which ? o : fmaf(tanhf(o), scale_w[l], scale_b[l]) * INV_LN2;
    }
    __syncthreads();

    for (int c = threadIdx.x; c < CELLS; c += blockDim.x) {
        const int base = (c < FINE_CELLS) ? c : (c + 1);
        float lo = nodes[base], hi = nodes[base + 1];
        float slope = hi - lo;                          // per index step
        float vmid  = 0.5f * (lo + hi);                 // value at cell center
        __half2 h2 = __floats2half2_rn(slope, vmid);    // low = m, high = v
        ((__half2*)ws)[(size_t)(l * CELLS + c) * 2 + which] = h2;
    }
}

// ---------------- index + center-offset (index units) ----------------
// Fine: u = 128x+256 in [0,512), trunc == floor. Coarse: clamp index to
// [512,639]; du uses the UNCLAMPED u so end cells extrapolate linearly.
__device__ __forceinline__ void cell_addr(float x, int* idx, float* du) {
    float uf = fmaf(x, 128.0f, 256.0f);
    float uc = fmaf(x, 2.0f, 576.0f);
    bool fine = (fabsf(x) < 2.0f);
    float ucl = fminf(fmaxf(uc, 512.0f), 639.0f);   // v_med3_f32
    float fi = fine ? uf : ucl;          // for index
    int i = (int)fi;                     // trunc == floor (u >= 0)
    float u = fine ? uf : uc;            // unclamped for du
    *idx = i;
    *du = u - (float)i - 0.5f;           // index-space offset from cell center
}

// ---------------- main flow: f16 table in LDS, 512-thread blocks --------------
// Geometry reasoning (R8 postmortem): with 76800 B LDS the compiler heuristic
// targets the LDS-limited occupancy. At TPB=512: 2 blocks/CU = 16 waves/CU =
// 4 waves/SIMD -> VGPR budget 128, so the allocator is free (R8's 1024-thread
// block got clamped to 32 VGPR -> gather ILP collapsed to ~1-deep, 42.8 us
// with BOTH pipes under 60%). CH=8 independent chains (24 live state floats)
// cannot fit in 32 VGPR, forcing a ~70-90 VGPR schedule with 8 back-to-back
// ds_read_b64 per layer step. NEVER pass a 2nd __launch_bounds__ arg (R3/R7).
__global__ __launch_bounds__(TPB) void flow_lut(
    const float4* __restrict__ x,      // pairs of float2 samples
    const float4* __restrict__ ws,     // staged f16 cell table
    float4* __restrict__ out_z,
    float2* __restrict__ out_ld,
    int npair)
{
    __shared__ __align__(16) uint2 lds[TABLE_CELLS];   // 76800 B -> 2 blocks/CU
    {
        float4* dst = (float4*)lds;
        for (int i = threadIdx.x; i < TABLE_CELLS / 2; i += blockDim.x) dst[i] = ws[i];
    }
    __syncthreads();

    const int tid = blockIdx.x * blockDim.x + threadIdx.x;
    const int stride = gridDim.x * blockDim.x;
    const int NP = CH / 2;               // float4 pairs per iteration

    for (int p0 = tid; p0 < npair; p0 += NP * stride) {
        float z1[CH], z2[CH], ld[CH];
#pragma unroll
        for (int q = 0; q < NP; ++q) {
            int p = p0 + q * stride;
            float4 xi = (p < npair) ? x[p] : make_float4(0.f, 0.f, 0.f, 0.f);
            z1[2*q]   = xi.y; z2[2*q]   = xi.x; ld[2*q]   = 0.f;
            z1[2*q+1] = xi.w; z2[2*q+1] = xi.z; ld[2*q+1] = 0.f;
        }

#pragma unroll
        for (int l = 0; l < NLAYER; ++l) {
            const uint2* T = lds + l * CELLS;
            int   idx[CH];
            float du[CH];
            uint2 cell[CH];
#pragma unroll
            for (int k = 0; k < CH; ++k) cell_addr(z2[k], &idx[k], &du[k]);
#pragma unroll
            for (int k = 0; k < CH; ++k) cell[k] = T[idx[k]];   // 8 gathers in flight
#pragma unroll
            for (int k = 0; k < CH; ++k) {
                __half2 sh = *(const __half2*)&cell[k].x;       // (s_m, s_v)
                __half2 th = *(const __half2*)&cell[k].y;       // (t_m, t_v)
                float ls = fmaf(__low2float(sh), du[k], __high2float(sh)); // log2 scale
                float g  = fmaf(__low2float(th), du[k], __high2float(th));
                float z2n = fmaf(fast_exp2(ls), z1[k], g);
                z1[k] = z2[k]; z2[k] = z2n; ld[k] += ls;
            }
        }

#pragma unroll
        for (int q = 0; q < NP; ++q) {
            int p = p0 + q * stride;
            if (p < npair) {
                out_z[p]  = make_float4(z1[2*q], z2[2*q], z1[2*q+1], z2[2*q+1]);
                out_ld[p] = make_float2(ld[2*q] * LN2F, ld[2*q+1] * LN2F);
            }
        }
    }
}

extern "C" void kernel_launch(void* const* d_in, const int* in_sizes, int n_in,
                              void* d_out, int out_size, void* d_ws, size_t ws_size,
                              hipStream_t stream) {
    const int n = in_sizes[0] / 2;
    const int npair = n / 2;             // N = 4194304 is even

    const float4* x       = (const float4*)d_in[0];
    const float*  scale_w = (const float*)d_in[1];
    const float*  scale_b = (const float*)d_in[2];
    const float*  sW1     = (const float*)d_in[3];
    const float*  sb1     = (const float*)d_in[4];
    const float*  sW2     = (const float*)d_in[5];
    const float*  sb2     = (const float*)d_in[6];
    const float*  sW3     = (const float*)d_in[7];
    const float*  sb3     = (const float*)d_in[8];
    const float*  tW1     = (const float*)d_in[9];
    const float*  tb1     = (const float*)d_in[10];
    const float*  tW2     = (const float*)d_in[11];
    const float*  tb2     = (const float*)d_in[12];
    const float*  tW3     = (const float*)d_in[13];
    const float*  tb3     = (const float*)d_in[14];

    float4* out_z  = (float4*)d_out;
    float2* out_ld = (float2*)((float*)d_out + (size_t)2 * n);

    build_tables<<<30, 640, 0, stream>>>(scale_w, scale_b,
        sW1, sb1, sW2, sb2, sW3, sb3,
        tW1, tb1, tW2, tb2, tW3, tb3, (float*)d_ws);

    // 512 blocks x 512 threads: 262144 threads, 8 pairs/thread (2 outer iters)
    const int nblocks = 512;
    flow_lut<<<nblocks, TPB, 0, stream>>>(x, (const float4*)d_ws, out_z, out_ld, npair);
}

// Round 11
// 153.595 us; speedup vs baseline: 1.0153x; 1.0153x over previous
//
#include <hip/hip_runtime.h>
#include <hip/hip_fp16.h>
#include <math.h>

#define SLOPE 0.01f
#define NLAYER 15
#define FINE_CELLS 512            // [-2, 2), h = 1/128
#define COARSE_CELLS 128          // [-32, 32), h = 1/2; extrapolate via clamped end cells
#define CELLS 640                 // per layer; cell = uint2: half2(s_m,s_v), half2(t_m,t_v)
#define FINE_NODES 513
#define NODES_PER_NET 642
#define TABLE_CELLS (NLAYER * CELLS)     // 9600 uint2 = 76800 B
#define LDS_PAD 642                      // pad to 81936 B: > 80 KiB so the compiler
                                         // sees 1 block/CU max -> VGPR budget 128
                                         // (R7/R8: 76800 B -> heuristic self-capped
                                         // to 32 VGPR and gather ILP collapsed)
#define INV_LN2 1.4426950408889634f
#define LN2F 0.6931471805599453f

__device__ __forceinline__ float fast_exp2(float x) {
#if __has_builtin(__builtin_amdgcn_exp2f)
    return __builtin_amdgcn_exp2f(x);
#else
    return __expf(x * LN2F);
#endif
}

// ---------------- exact scalar->32->16->1 MLP (precompute only) ----------------
__device__ __forceinline__ float mlp_exact(
    float x1,
    const float* __restrict__ W1, const float* __restrict__ b1,
    const float* __restrict__ W2, const float* __restrict__ b2,
    const float* __restrict__ W3, float b3)
{
    float h2[16];
#pragma unroll
    for (int n = 0; n < 16; ++n) h2[n] = b2[n];
#pragma unroll 2
    for (int j = 0; j < 32; ++j) {
        float h = fmaf(W1[j], x1, b1[j]);
        h = fmaxf(h, SLOPE * h);
#pragma unroll
        for (int n = 0; n < 16; ++n) h2[n] = fmaf(h, W2[j * 16 + n], h2[n]);
    }
    float o = b3;
#pragma unroll
    for (int n = 0; n < 16; ++n) {
        float h = fmaxf(h2[n], SLOPE * h2[n]);
        o = fmaf(h, W3[n], o);
    }
    return o;
}

// ---------------- build: one block per net (30 blocks) ----
// Cell stores CENTER-REFERENCED f16 (slope-per-index-step, center value):
//   val(u) = m*(u - i - 0.5) + v,  u = index-space coordinate, m = hi - lo.
// |du| <= 0.5 so f16 error hits v (rel 2^-11) and m*du (tiny).
// s-net values are in log2 units. (Accuracy verified R7/R8: absmax 0.125.)
__global__ __launch_bounds__(640) void build_tables(
    const float* __restrict__ scale_w, const float* __restrict__ scale_b,
    const float* __restrict__ sW1, const float* __restrict__ sb1,
    const float* __restrict__ sW2, const float* __restrict__ sb2,
    const float* __restrict__ sW3, const float* __restrict__ sb3,
    const float* __restrict__ tW1, const float* __restrict__ tb1,
    const float* __restrict__ tW2, const float* __restrict__ tb2,
    const float* __restrict__ tW3, const float* __restrict__ tb3,
    float* __restrict__ ws)
{
    const int m = blockIdx.x;            // 0..29
    const int l = m >> 1;
    const int which = m & 1;             // 0 = s-net, 1 = t-net
    const float* W1 = (which ? tW1 : sW1) + l * 32;
    const float* b1 = (which ? tb1 : sb1) + l * 32;
    const float* W2 = (which ? tW2 : sW2) + l * 512;
    const float* b2 = (which ? tb2 : sb2) + l * 16;
    const float* W3 = (which ? tW3 : sW3) + l * 16;
    const float  b3 = which ? tb3[l] : sb3[l];

    __shared__ float nodes[NODES_PER_NET];

    for (int i = threadIdx.x; i < NODES_PER_NET; i += blockDim.x) {
        const float x = (i < FINE_NODES) ? (-2.0f + (float)i * (1.0f / 128.0f))
                                         : (-32.0f + (float)(i - FINE_NODES) * 0.5f);
        float o = mlp_exact(x, W1, b1, W2, b2, W3, b3);
        nodes[i] = which ? o : fmaf(tanhf(o), scale_w[l], scale_b[l]) * INV_LN2;
    }
    __syncthreads();

    for (int c = threadIdx.x; c < CELLS; c += blockDim.x) {
        const int base = (c < FINE_CELLS) ? c : (c + 1);
        float lo = nodes[base], hi = nodes[base + 1];
        float slope = hi - lo;                          // per index step
        float vmid  = 0.5f * (lo + hi);                 // value at cell center
        __half2 h2 = __floats2half2_rn(slope, vmid);    // low = m, high = v
        ((__half2*)ws)[(size_t)(l * CELLS + c) * 2 + which] = h2;
    }
}

// ---------------- index + center-offset (index units) ----------------
// Fine: u = 128x+256 in [0,512), trunc == floor. Coarse: clamp index to
// [512,639]; du uses the UNCLAMPED u so end cells extrapolate linearly.
__device__ __forceinline__ void cell_addr(float x, int* idx, float* du) {
    float uf = fmaf(x, 128.0f, 256.0f);
    float uc = fmaf(x, 2.0f, 576.0f);
    bool fine = (fabsf(x) < 2.0f);
    float ucl = fminf(fmaxf(uc, 512.0f), 639.0f);   // v_med3_f32
    float fi = fine ? uf : ucl;          // for index
    int i = (int)fi;                     // trunc == floor (u >= 0)
    float u = fine ? uf : uc;            // unclamped for du
    *idx = i;
    *du = u - (float)i - 0.5f;           // index-space offset from cell center
}

// ---------------- main flow: R6 structure + f16 table + LDS pad ---------------
// 256 blocks x 1024 threads = 1 block/CU, 16 waves/CU, zero barriers in the
// main loop, 4 independent chains per thread iteration, per-chain interleaved
// code (NOT R9's batched arrays). LDS padded past 80 KiB so the compiler's
// occupancy heuristic grants the 128-VGPR budget (R10 decisive check).
// NEVER pass a 2nd __launch_bounds__ arg (R3/R7: forces a 32-VGPR clamp).
__global__ __launch_bounds__(1024) void flow_lut(
    const float4* __restrict__ x,      // pairs of float2 samples
    const float4* __restrict__ ws,     // staged f16 cell table
    float4* __restrict__ out_z,
    float2* __restrict__ out_ld,
    int npair)
{
    __shared__ __align__(16) uint2 lds[TABLE_CELLS + LDS_PAD];   // 81936 B
    {
        float4* dst = (float4*)lds;
        for (int i = threadIdx.x; i < TABLE_CELLS / 2; i += blockDim.x) dst[i] = ws[i];
    }
    __syncthreads();

    const int tid = blockIdx.x * blockDim.x + threadIdx.x;
    const int stride = gridDim.x * blockDim.x;

    for (int p0 = tid; p0 < npair; p0 += 2 * stride) {
        const int p1 = p0 + stride;
        const bool has1 = (p1 < npair);
        float4 xa = x[p0];
        float4 xb = has1 ? x[p1] : make_float4(0.f, 0.f, 0.f, 0.f);

        float az1 = xa.y, az2 = xa.x, ald = 0.f;
        float bz1 = xa.w, bz2 = xa.z, bld = 0.f;
        float cz1 = xb.y, cz2 = xb.x, cld = 0.f;
        float dz1 = xb.w, dz2 = xb.z, dld = 0.f;

#pragma unroll
        for (int l = 0; l < NLAYER; ++l) {
            const uint2* T = lds + l * CELLS;
            int ia, ib, ic, id;
            float dua, dub, duc, dud;
            cell_addr(az2, &ia, &dua);
            cell_addr(bz2, &ib, &dub);
            cell_addr(cz2, &ic, &duc);
            cell_addr(dz2, &id, &dud);
            // 4 independent b64 gathers in flight before any dependent VALU
            uint2 ca = T[ia];
            uint2 cb = T[ib];
            uint2 cc = T[ic];
            uint2 cd = T[id];

            __half2 ash = *(const __half2*)&ca.x, ath = *(const __half2*)&ca.y;
            __half2 bsh = *(const __half2*)&cb.x, bth = *(const __half2*)&cb.y;
            __half2 csh = *(const __half2*)&cc.x, cth = *(const __half2*)&cc.y;
            __half2 dsh = *(const __half2*)&cd.x, dth = *(const __half2*)&cd.y;

            float als = fmaf(__low2float(ash), dua, __high2float(ash));
            float ag  = fmaf(__low2float(ath), dua, __high2float(ath));
            float bls = fmaf(__low2float(bsh), dub, __high2float(bsh));
            float bg  = fmaf(__low2float(bth), dub, __high2float(bth));
            float cls = fmaf(__low2float(csh), duc, __high2float(csh));
            float cg  = fmaf(__low2float(cth), duc, __high2float(cth));
            float dls = fmaf(__low2float(dsh), dud, __high2float(dsh));
            float dg  = fmaf(__low2float(dth), dud, __high2float(dth));

            float az2n = fmaf(fast_exp2(als), az1, ag);
            float bz2n = fmaf(fast_exp2(bls), bz1, bg);
            float cz2n = fmaf(fast_exp2(cls), cz1, cg);
            float dz2n = fmaf(fast_exp2(dls), dz1, dg);

            az1 = az2; az2 = az2n; ald += als;
            bz1 = bz2; bz2 = bz2n; bld += bls;
            cz1 = cz2; cz2 = cz2n; cld += cls;
            dz1 = dz2; dz2 = dz2n; dld += dls;
        }

        out_z[p0]  = make_float4(az1, az2, bz1, bz2);
        out_ld[p0] = make_float2(ald * LN2F, bld * LN2F);
        if (has1) {
            out_z[p1]  = make_float4(cz1, cz2, dz1, dz2);
            out_ld[p1] = make_float2(cld * LN2F, dld * LN2F);
        }
    }
}

extern "C" void kernel_launch(void* const* d_in, const int* in_sizes, int n_in,
                              void* d_out, int out_size, void* d_ws, size_t ws_size,
                              hipStream_t stream) {
    const int n = in_sizes[0] / 2;
    const int npair = n / 2;             // N = 4194304 is even

    const float4* x       = (const float4*)d_in[0];
    const float*  scale_w = (const float*)d_in[1];
    const float*  scale_b = (const float*)d_in[2];
    const float*  sW1     = (const float*)d_in[3];
    const float*  sb1     = (const float*)d_in[4];
    const float*  sW2     = (const float*)d_in[5];
    const float*  sb2     = (const float*)d_in[6];
    const float*  sW3     = (const float*)d_in[7];
    const float*  sb3     = (const float*)d_in[8];
    const float*  tW1     = (const float*)d_in[9];
    const float*  tb1     = (const float*)d_in[10];
    const float*  tW2     = (const float*)d_in[11];
    const float*  tb2     = (const float*)d_in[12];
    const float*  tW3     = (const float*)d_in[13];
    const float*  tb3     = (const float*)d_in[14];

    float4* out_z  = (float4*)d_out;
    float2* out_ld = (float2*)((float*)d_out + (size_t)2 * n);

    build_tables<<<30, 640, 0, stream>>>(scale_w, scale_b,
        sW1, sb1, sW2, sb2, sW3, sb3,
        tW1, tb1, tW2, tb2, tW3, tb3, (float*)d_ws);

    flow_lut<<<256, 1024, 0, stream>>>(x, (const float4*)d_ws, out_z, out_ld, npair);
}

// Round 12
// 153.517 us; speedup vs baseline: 1.0158x; 1.0005x over previous
//
#include <hip/hip_runtime.h>
#include <math.h>

#define SLOPE 0.01f
#define NLAYER 15
#define FINE_CELLS 512            // [-2, 2), h = 1/128
#define COARSE_CELLS 128          // [-32, 32), h = 1/2; extrapolate via clamped end cells
#define CELLS 640                 // per layer; cell = float4 (s_m, s_c, t_m, t_c) slope/intercept
#define FINE_NODES 513
#define NODES_PER_NET 642
#define TABLE_FLOAT4 (NLAYER * CELLS)        // 9600 float4 = 153600 B
#define INV_LN2 1.4426950408889634f
#define LN2F 0.6931471805599453f
#define CH 8                      // independent chains per thread iteration

__device__ __forceinline__ float fast_exp2(float x) {
#if __has_builtin(__builtin_amdgcn_exp2f)
    return __builtin_amdgcn_exp2f(x);
#else
    return __expf(x * LN2F);
#endif
}

// ---------------- exact scalar->32->16->1 MLP (precompute only) ----------------
__device__ __forceinline__ float mlp_exact(
    float x1,
    const float* __restrict__ W1, const float* __restrict__ b1,
    const float* __restrict__ W2, const float* __restrict__ b2,
    const float* __restrict__ W3, float b3)
{
    float h2[16];
#pragma unroll
    for (int n = 0; n < 16; ++n) h2[n] = b2[n];
#pragma unroll 2
    for (int j = 0; j < 32; ++j) {
        float h = fmaf(W1[j], x1, b1[j]);
        h = fmaxf(h, SLOPE * h);
#pragma unroll
        for (int n = 0; n < 16; ++n) h2[n] = fmaf(h, W2[j * 16 + n], h2[n]);
    }
    float o = b3;
#pragma unroll
    for (int n = 0; n < 16; ++n) {
        float h = fmaxf(h2[n], SLOPE * h2[n]);
        o = fmaf(h, W3[n], o);
    }
    return o;
}

// ---------------- build: one block per net (30 blocks) ----
// Cell c stores slope/intercept so eval is a single fma in x:
//   which==0 (s-net): (.x,.y) = (m, c) with ls2(x) = m*x + c   [log2 units]
//   which==1 (t-net): (.z,.w) = (m, c) with g(x)   = m*x + c
// (verified: absmax 0.125 — R5/R6)
__global__ __launch_bounds__(640) void build_tables(
    const float* __restrict__ scale_w, const float* __restrict__ scale_b,
    const float* __restrict__ sW1, const float* __restrict__ sb1,
    const float* __restrict__ sW2, const float* __restrict__ sb2,
    const float* __restrict__ sW3, const float* __restrict__ sb3,
    const float* __restrict__ tW1, const float* __restrict__ tb1,
    const float* __restrict__ tW2, const float* __restrict__ tb2,
    const float* __restrict__ tW3, const float* __restrict__ tb3,
    float* __restrict__ ws)
{
    const int m = blockIdx.x;            // 0..29
    const int l = m >> 1;
    const int which = m & 1;             // 0 = s-net, 1 = t-net
    const float* W1 = (which ? tW1 : sW1) + l * 32;
    const float* b1 = (which ? tb1 : sb1) + l * 32;
    const float* W2 = (which ? tW2 : sW2) + l * 512;
    const float* b2 = (which ? tb2 : sb2) + l * 16;
    const float* W3 = (which ? tW3 : sW3) + l * 16;
    const float  b3 = which ? tb3[l] : sb3[l];

    __shared__ float nodes[NODES_PER_NET];

    for (int i = threadIdx.x; i < NODES_PER_NET; i += blockDim.x) {
        const float x = (i < FINE_NODES) ? (-2.0f + (float)i * (1.0f / 128.0f))
                                         : (-32.0f + (float)(i - FINE_NODES) * 0.5f);
        float o = mlp_exact(x, W1, b1, W2, b2, W3, b3);
        nodes[i] = which ? o : fmaf(tanhf(o), scale_w[l], scale_b[l]) * INV_LN2;
    }
    __syncthreads();

    for (int c = threadIdx.x; c < CELLS; c += blockDim.x) {
        int base; float x_lo, invh;
        if (c < FINE_CELLS) { base = c;     x_lo = -2.0f  + (float)c * (1.0f / 128.0f); invh = 128.0f; }
        else                { base = c + 1; x_lo = -32.0f + (float)(c - FINE_CELLS) * 0.5f; invh = 2.0f; }
        float lo = nodes[base], hi = nodes[base + 1];
        float slope = (hi - lo) * invh;
        float icpt  = fmaf(-slope, x_lo, lo);
        *(float2*)(ws + ((size_t)(l * CELLS + c) * 4) + which * 2) = make_float2(slope, icpt);
    }
}

// ---------------- cell index ----------------
// Fine: uf = 128x+256 in [0,512) -> trunc == floor (non-negative).
// Coarse: med3-clamp to [512,639] in float, then one cvt.
__device__ __forceinline__ int cell_index(float x) {
    float uf = fmaf(x, 128.0f, 256.0f);
    float uc = fmaf(x, 2.0f, 576.0f);
    float ucl = fminf(fmaxf(uc, 512.0f), 639.0f);   // -> v_med3_f32
    float u = (fabsf(x) < 2.0f) ? uf : ucl;
    return (int)u;
}

// ---------------- main flow: R6 structure, CH=8 chains/thread -----------------
// 256 blocks x 1024 threads = 1 block/CU (LDS 153600 B -> compiler VGPR budget
// 128, allocator free; R4 allocated 100 in this regime), 16 waves/CU, zero
// barriers in the main loop. Measured ladder: 2 chains ~40us (R5), 4 chains
// ~37us (R6); kernel is latency-bound (R11: both pipes <60% busy), so CH=8
// doubles the in-flight ds_read_b128 queue per wave. f16/b64 table is
// 3x-measured SLOWER (43us, R7/R8/R11) despite halved bank conflicts — the
// cvt chain lengthens the dependent path; conflicts are not the binding cost.
// NEVER pass a 2nd __launch_bounds__ arg (R3/R7: 32-VGPR clamp).
__global__ __launch_bounds__(1024) void flow_lut(
    const float4* __restrict__ x,      // pairs of float2 samples
    const float4* __restrict__ ws,     // [NLAYER][CELLS] slope/intercept cells
    float4* __restrict__ out_z,
    float2* __restrict__ out_ld,
    int npair)
{
    __shared__ __align__(16) float4 lds[TABLE_FLOAT4];   // 153600 B
    for (int i = threadIdx.x; i < TABLE_FLOAT4; i += blockDim.x) lds[i] = ws[i];
    __syncthreads();

    const int tid = blockIdx.x * blockDim.x + threadIdx.x;
    const int stride = gridDim.x * blockDim.x;
    const int NP = CH / 2;               // float4 pairs per iteration (4)

    for (int p0 = tid; p0 < npair; p0 += NP * stride) {
        float z1[CH], z2[CH], ld[CH];
#pragma unroll
        for (int q = 0; q < NP; ++q) {
            int p = p0 + q * stride;
            float4 xi = (p < npair) ? x[p] : make_float4(0.f, 0.f, 0.f, 0.f);
            z1[2*q]   = xi.y; z2[2*q]   = xi.x; ld[2*q]   = 0.f;
            z1[2*q+1] = xi.w; z2[2*q+1] = xi.z; ld[2*q+1] = 0.f;
        }

#pragma unroll
        for (int l = 0; l < NLAYER; ++l) {
            const float4* T = lds + l * CELLS;
            float4 cell[CH];
#pragma unroll
            for (int k = 0; k < CH; ++k) cell[k] = T[cell_index(z2[k])];  // 8 b128 in flight
#pragma unroll
            for (int k = 0; k < CH; ++k) {
                float ls = fmaf(cell[k].x, z2[k], cell[k].y);   // log2 scale
                float g  = fmaf(cell[k].z, z2[k], cell[k].w);
                float z2n = fmaf(fast_exp2(ls), z1[k], g);
                z1[k] = z2[k]; z2[k] = z2n; ld[k] += ls;
            }
        }

#pragma unroll
        for (int q = 0; q < NP; ++q) {
            int p = p0 + q * stride;
            if (p < npair) {
                out_z[p]  = make_float4(z1[2*q], z2[2*q], z1[2*q+1], z2[2*q+1]);
                out_ld[p] = make_float2(ld[2*q] * LN2F, ld[2*q+1] * LN2F);
            }
        }
    }
}

extern "C" void kernel_launch(void* const* d_in, const int* in_sizes, int n_in,
                              void* d_out, int out_size, void* d_ws, size_t ws_size,
                              hipStream_t stream) {
    const int n = in_sizes[0] / 2;
    const int npair = n / 2;             // N = 4194304 is even

    const float4* x       = (const float4*)d_in[0];
    const float*  scale_w = (const float*)d_in[1];
    const float*  scale_b = (const float*)d_in[2];
    const float*  sW1     = (const float*)d_in[3];
    const float*  sb1     = (const float*)d_in[4];
    const float*  sW2     = (const float*)d_in[5];
    const float*  sb2     = (const float*)d_in[6];
    const float*  sW3     = (const float*)d_in[7];
    const float*  sb3     = (const float*)d_in[8];
    const float*  tW1     = (const float*)d_in[9];
    const float*  tb1     = (const float*)d_in[10];
    const float*  tW2     = (const float*)d_in[11];
    const float*  tb2     = (const float*)d_in[12];
    const float*  tW3     = (const float*)d_in[13];
    const float*  tb3     = (const float*)d_in[14];

    float4* out_z  = (float4*)d_out;
    float2* out_ld = (float2*)((float*)d_out + (size_t)2 * n);

    build_tables<<<30, 640, 0, stream>>>(scale_w, scale_b,
        sW1, sb1, sW2, sb2, sW3, sb3,
        tW1, tb1, tW2, tb2, tW3, tb3, (float*)d_ws);

    flow_lut<<<256, 1024, 0, stream>>>(x, (const float4*)d_ws, out_z, out_ld, npair);
}

// Round 13
// 149.647 us; speedup vs baseline: 1.0421x; 1.0259x over previous
//
#include <hip/hip_runtime.h>
#include <math.h>

#define SLOPE 0.01f
#define NLAYER 15
#define FINE_CELLS 512            // [-2, 2), h = 1/128
#define COARSE_CELLS 128          // [-32, 32), h = 1/2; extrapolate via clamped end cells
#define CELLS 640                 // per layer; cell = float4 (s_m, s_c, t_m, t_c) slope/intercept
#define FINE_NODES 513
#define NODES_PER_NET 642
#define TABLE_FLOAT4 (NLAYER * CELLS)        // 9600 float4 = 153600 B
#define INV_LN2 1.4426950408889634f
#define LN2F 0.6931471805599453f
#define CH 6                      // independent chains per thread iteration
                                  // R12: CH=8 needs ~85 VGPR -> spilled at the
                                  // allocator's 64-VGPR ceiling (WRITE 49->63MB).
                                  // CH=6 ~62 regs: the last untested ILP point.

__device__ __forceinline__ float fast_exp2(float x) {
#if __has_builtin(__builtin_amdgcn_exp2f)
    return __builtin_amdgcn_exp2f(x);
#else
    return __expf(x * LN2F);
#endif
}

// ---------------- exact scalar->32->16->1 MLP (precompute only) ----------------
__device__ __forceinline__ float mlp_exact(
    float x1,
    const float* __restrict__ W1, const float* __restrict__ b1,
    const float* __restrict__ W2, const float* __restrict__ b2,
    const float* __restrict__ W3, float b3)
{
    float h2[16];
#pragma unroll
    for (int n = 0; n < 16; ++n) h2[n] = b2[n];
#pragma unroll 2
    for (int j = 0; j < 32; ++j) {
        float h = fmaf(W1[j], x1, b1[j]);
        h = fmaxf(h, SLOPE * h);
#pragma unroll
        for (int n = 0; n < 16; ++n) h2[n] = fmaf(h, W2[j * 16 + n], h2[n]);
    }
    float o = b3;
#pragma unroll
    for (int n = 0; n < 16; ++n) {
        float h = fmaxf(h2[n], SLOPE * h2[n]);
        o = fmaf(h, W3[n], o);
    }
    return o;
}

// ---------------- build: one block per net (30 blocks) ----
// Cell c stores slope/intercept so eval is a single fma in x:
//   which==0 (s-net): (.x,.y) = (m, c) with ls2(x) = m*x + c   [log2 units]
//   which==1 (t-net): (.z,.w) = (m, c) with g(x)   = m*x + c
// (verified: absmax 0.125 — R5/R6/R12)
__global__ __launch_bounds__(640) void build_tables(
    const float* __restrict__ scale_w, const float* __restrict__ scale_b,
    const float* __restrict__ sW1, const float* __restrict__ sb1,
    const float* __restrict__ sW2, const float* __restrict__ sb2,
    const float* __restrict__ sW3, const float* __restrict__ sb3,
    const float* __restrict__ tW1, const float* __restrict__ tb1,
    const float* __restrict__ tW2, const float* __restrict__ tb2,
    const float* __restrict__ tW3, const float* __restrict__ tb3,
    float* __restrict__ ws)
{
    const int m = blockIdx.x;            // 0..29
    const int l = m >> 1;
    const int which = m & 1;             // 0 = s-net, 1 = t-net
    const float* W1 = (which ? tW1 : sW1) + l * 32;
    const float* b1 = (which ? tb1 : sb1) + l * 32;
    const float* W2 = (which ? tW2 : sW2) + l * 512;
    const float* b2 = (which ? tb2 : sb2) + l * 16;
    const float* W3 = (which ? tW3 : sW3) + l * 16;
    const float  b3 = which ? tb3[l] : sb3[l];

    __shared__ float nodes[NODES_PER_NET];

    for (int i = threadIdx.x; i < NODES_PER_NET; i += blockDim.x) {
        const float x = (i < FINE_NODES) ? (-2.0f + (float)i * (1.0f / 128.0f))
                                         : (-32.0f + (float)(i - FINE_NODES) * 0.5f);
        float o = mlp_exact(x, W1, b1, W2, b2, W3, b3);
        nodes[i] = which ? o : fmaf(tanhf(o), scale_w[l], scale_b[l]) * INV_LN2;
    }
    __syncthreads();

    for (int c = threadIdx.x; c < CELLS; c += blockDim.x) {
        int base; float x_lo, invh;
        if (c < FINE_CELLS) { base = c;     x_lo = -2.0f  + (float)c * (1.0f / 128.0f); invh = 128.0f; }
        else                { base = c + 1; x_lo = -32.0f + (float)(c - FINE_CELLS) * 0.5f; invh = 2.0f; }
        float lo = nodes[base], hi = nodes[base + 1];
        float slope = (hi - lo) * invh;
        float icpt  = fmaf(-slope, x_lo, lo);
        *(float2*)(ws + ((size_t)(l * CELLS + c) * 4) + which * 2) = make_float2(slope, icpt);
    }
}

// ---------------- cell index ----------------
// Fine: uf = 128x+256 in [0,512) -> trunc == floor (non-negative).
// Coarse: med3-clamp to [512,639] in float, then one cvt.
__device__ __forceinline__ int cell_index(float x) {
    float uf = fmaf(x, 128.0f, 256.0f);
    float uc = fmaf(x, 2.0f, 576.0f);
    float ucl = fminf(fmaxf(uc, 512.0f), 639.0f);   // -> v_med3_f32
    float u = (fabsf(x) < 2.0f) ? uf : ucl;
    return (int)u;
}

// ---------------- main flow: R6 structure, CH=6 chains/thread -----------------
// 256 blocks x 1024 threads = 1 block/CU (LDS 153600 B), 16 waves/CU, zero
// barriers in the main loop. Latency-bound (R11: both pipes <60%); ILP ladder:
// 2 chains ~40us (R5), 4 ~37us (R6), 8 = spill at the 64-VGPR allocator
// ceiling (R12: WRITE 49->63MB). CH=6 (~62 regs) is the last point under the
// ceiling. f16/b64 table 3x-measured slower (R7/R8/R11) — stay f32/b128.
// NEVER pass a 2nd __launch_bounds__ arg (R3/R7: 32-VGPR clamp).
__global__ __launch_bounds__(1024) void flow_lut(
    const float4* __restrict__ x,      // pairs of float2 samples
    const float4* __restrict__ ws,     // [NLAYER][CELLS] slope/intercept cells
    float4* __restrict__ out_z,
    float2* __restrict__ out_ld,
    int npair)
{
    __shared__ __align__(16) float4 lds[TABLE_FLOAT4];   // 153600 B
    for (int i = threadIdx.x; i < TABLE_FLOAT4; i += blockDim.x) lds[i] = ws[i];
    __syncthreads();

    const int tid = blockIdx.x * blockDim.x + threadIdx.x;
    const int stride = gridDim.x * blockDim.x;
    const int NP = CH / 2;               // float4 pairs per iteration (3)

    for (int p0 = tid; p0 < npair; p0 += NP * stride) {
        float z1[CH], z2[CH], ld[CH];
#pragma unroll
        for (int q = 0; q < NP; ++q) {
            int p = p0 + q * stride;
            float4 xi = (p < npair) ? x[p] : make_float4(0.f, 0.f, 0.f, 0.f);
            z1[2*q]   = xi.y; z2[2*q]   = xi.x; ld[2*q]   = 0.f;
            z1[2*q+1] = xi.w; z2[2*q+1] = xi.z; ld[2*q+1] = 0.f;
        }

#pragma unroll
        for (int l = 0; l < NLAYER; ++l) {
            const float4* T = lds + l * CELLS;
            float4 cell[CH];
#pragma unroll
            for (int k = 0; k < CH; ++k) cell[k] = T[cell_index(z2[k])];  // 6 b128 in flight
#pragma unroll
            for (int k = 0; k < CH; ++k) {
                float ls = fmaf(cell[k].x, z2[k], cell[k].y);   // log2 scale
                float g  = fmaf(cell[k].z, z2[k], cell[k].w);
                float z2n = fmaf(fast_exp2(ls), z1[k], g);
                z1[k] = z2[k]; z2[k] = z2n; ld[k] += ls;
            }
        }

#pragma unroll
        for (int q = 0; q < NP; ++q) {
            int p = p0 + q * stride;
            if (p < npair) {
                out_z[p]  = make_float4(z1[2*q], z2[2*q], z1[2*q+1], z2[2*q+1]);
                out_ld[p] = make_float2(ld[2*q] * LN2F, ld[2*q+1] * LN2F);
            }
        }
    }
}

extern "C" void kernel_launch(void* const* d_in, const int* in_sizes, int n_in,
                              void* d_out, int out_size, void* d_ws, size_t ws_size,
                              hipStream_t stream) {
    const int n = in_sizes[0] / 2;
    const int npair = n / 2;             // N = 4194304 is even

    const float4* x       = (const float4*)d_in[0];
    const float*  scale_w = (const float*)d_in[1];
    const float*  scale_b = (const float*)d_in[2];
    const float*  sW1     = (const float*)d_in[3];
    const float*  sb1     = (const float*)d_in[4];
    const float*  sW2     = (const float*)d_in[5];
    const float*  sb2     = (const float*)d_in[6];
    const float*  sW3     = (const float*)d_in[7];
    const float*  sb3     = (const float*)d_in[8];
    const float*  tW1     = (const float*)d_in[9];
    const float*  tb1     = (const float*)d_in[10];
    const float*  tW2     = (const float*)d_in[11];
    const float*  tb2     = (const float*)d_in[12];
    const float*  tW3     = (const float*)d_in[13];
    const float*  tb3     = (const float*)d_in[14];

    float4* out_z  = (float4*)d_out;
    float2* out_ld = (float2*)((float*)d_out + (size_t)2 * n);

    build_tables<<<30, 640, 0, stream>>>(scale_w, scale_b,
        sW1, sb1, sW2, sb2, sW3, sb3,
        tW1, tb1, tW2, tb2, tW3, tb3, (float*)d_ws);

    flow_lut<<<256, 1024, 0, stream>>>(x, (const float4*)d_ws, out_z, out_ld, npair);
}

// Round 15
// 147.897 us; speedup vs baseline: 1.0544x; 1.0118x over previous
//
#include <hip/hip_runtime.h>
#include <math.h>

#define SLOPE 0.01f
#define NLAYER 15
#define FINE_CELLS 512            // [-2, 2), h = 1/128
#define COARSE_CELLS 128          // [-32, 32), h = 1/2; extrapolate outside via clamped end cells
#define CELLS 640                 // per layer; cell = float4 (s_m, s_c, t_m, t_c) slope/intercept
#define FINE_NODES 513
#define NODES_PER_NET 642
#define TABLE_FLOAT4 (NLAYER * CELLS)        // 9600 float4 = 153600 B
#define INV_LN2 1.4426950408889634f
#define LN2F 0.6931471805599453f

__device__ __forceinline__ float fast_exp2(float x) {
#if __has_builtin(__builtin_amdgcn_exp2f)
    return __builtin_amdgcn_exp2f(x);
#else
    return __expf(x * LN2F);
#endif
}

// ---------------- exact scalar->32->16->1 MLP (precompute only) ----------------
__device__ __forceinline__ float mlp_exact(
    float x1,
    const float* __restrict__ W1, const float* __restrict__ b1,
    const float* __restrict__ W2, const float* __restrict__ b2,
    const float* __restrict__ W3, float b3)
{
    float h2[16];
#pragma unroll
    for (int n = 0; n < 16; ++n) h2[n] = b2[n];
#pragma unroll 2
    for (int j = 0; j < 32; ++j) {
        float h = fmaf(W1[j], x1, b1[j]);
        h = fmaxf(h, SLOPE * h);
#pragma unroll
        for (int n = 0; n < 16; ++n) h2[n] = fmaf(h, W2[j * 16 + n], h2[n]);
    }
    float o = b3;
#pragma unroll
    for (int n = 0; n < 16; ++n) {
        float h = fmaxf(h2[n], SLOPE * h2[n]);
        o = fmaf(h, W3[n], o);
    }
    return o;
}

// ---------------- build: one block per net (30 blocks) ----
// Cell c stores slope/intercept so eval is a single fma in x:
//   which==0 (s-net): (.x,.y) = (m, c) with ls2(x) = m*x + c   [log2 units]
//   which==1 (t-net): (.z,.w) = (m, c) with g(x)   = m*x + c
// ls stays LINEAR in the table; exp is applied exactly at eval time. R14 proved
// linearizing exp(ls) directly is numerically unsound on the coarse grid
// (curvature error ~E*(ls'h)^2/8 blows up at h=0.5: absmax 0.125 -> 1.16).
__global__ __launch_bounds__(640) void build_tables(
    const float* __restrict__ scale_w, const float* __restrict__ scale_b,
    const float* __restrict__ sW1, const float* __restrict__ sb1,
    const float* __restrict__ sW2, const float* __restrict__ sb2,
    const float* __restrict__ sW3, const float* __restrict__ sb3,
    const float* __restrict__ tW1, const float* __restrict__ tb1,
    const float* __restrict__ tW2, const float* __restrict__ tb2,
    const float* __restrict__ tW3, const float* __restrict__ tb3,
    float* __restrict__ ws)
{
    const int m = blockIdx.x;            // 0..29
    const int l = m >> 1;
    const int which = m & 1;             // 0 = s-net, 1 = t-net
    const float* W1 = (which ? tW1 : sW1) + l * 32;
    const float* b1 = (which ? tb1 : sb1) + l * 32;
    const float* W2 = (which ? tW2 : sW2) + l * 512;
    const float* b2 = (which ? tb2 : sb2) + l * 16;
    const float* W3 = (which ? tW3 : sW3) + l * 16;
    const float  b3 = which ? tb3[l] : sb3[l];

    __shared__ float nodes[NODES_PER_NET];

    for (int i = threadIdx.x; i < NODES_PER_NET; i += blockDim.x) {
        const float x = (i < FINE_NODES) ? (-2.0f + (float)i * (1.0f / 128.0f))
                                         : (-32.0f + (float)(i - FINE_NODES) * 0.5f);
        float o = mlp_exact(x, W1, b1, W2, b2, W3, b3);
        nodes[i] = which ? o : fmaf(tanhf(o), scale_w[l], scale_b[l]) * INV_LN2;
    }
    __syncthreads();

    for (int c = threadIdx.x; c < CELLS; c += blockDim.x) {
        int base; float x_lo, invh;
        if (c < FINE_CELLS) { base = c;     x_lo = -2.0f  + (float)c * (1.0f / 128.0f); invh = 128.0f; }
        else                { base = c + 1; x_lo = -32.0f + (float)(c - FINE_CELLS) * 0.5f; invh = 2.0f; }
        float lo = nodes[base], hi = nodes[base + 1];
        float slope = (hi - lo) * invh;
        float icpt  = fmaf(-slope, x_lo, lo);
        *(float2*)(ws + ((size_t)(l * CELLS + c) * 4) + which * 2) = make_float2(slope, icpt);
    }
}

// ---------------- cell index ----------------
// Fine: uf = 128x+256 in [0,512) -> trunc == floor (non-negative).
// Coarse: med3-clamp to [512,639] in float, then one cvt.
__device__ __forceinline__ int cell_index(float x) {
    float uf = fmaf(x, 128.0f, 256.0f);
    float uc = fmaf(x, 2.0f, 576.0f);
    float ucl = fminf(fmaxf(uc, 512.0f), 639.0f);   // -> v_med3_f32
    float u = (fabsf(x) < 2.0f) ? uf : ucl;
    return (int)u;
}

// ---------------- main flow: whole table in LDS (R6 configuration, FINAL) -----
// 256 blocks x 1024 threads = 1 block/CU (LDS 153600 B), 16 waves/CU, zero
// barriers in the main loop, 4 independent chains per thread iteration.
// Measured landscape (R0-R14): table layout f32/b128 best (f16/b64 3x slower
// despite halved conflicts); whole-table residency best (per-layer staging
// +28us); chain ILP 2->40us, 4->37us (optimum), 6 wastes 33% (6 doesn't
// divide 8 chains/thread), 8 spills at the 64-VGPR allocator ceiling;
// exp-free table numerically unsound (R14). NEVER pass a 2nd
// __launch_bounds__ arg (R3/R7: 32-VGPR clamp).
__global__ __launch_bounds__(1024) void flow_lut(
    const float4* __restrict__ x,      // pairs of float2 samples
    const float4* __restrict__ ws,     // [NLAYER][CELLS] slope/intercept cells
    float4* __restrict__ out_z,
    float2* __restrict__ out_ld,
    int npair)
{
    __shared__ __align__(16) float4 lds[TABLE_FLOAT4];   // 153600 B
    for (int i = threadIdx.x; i < TABLE_FLOAT4; i += blockDim.x) lds[i] = ws[i];
    __syncthreads();

    const int tid = blockIdx.x * blockDim.x + threadIdx.x;
    const int stride = gridDim.x * blockDim.x;

    for (int p0 = tid; p0 < npair; p0 += 2 * stride) {
        const int p1 = p0 + stride;
        const bool has1 = (p1 < npair);
        float4 xa = x[p0];
        float4 xb = has1 ? x[p1] : make_float4(0.f, 0.f, 0.f, 0.f);

        float az1 = xa.y, az2 = xa.x, ald = 0.f;
        float bz1 = xa.w, bz2 = xa.z, bld = 0.f;
        float cz1 = xb.y, cz2 = xb.x, cld = 0.f;
        float dz1 = xb.w, dz2 = xb.z, dld = 0.f;

#pragma unroll
        for (int l = 0; l < NLAYER; ++l) {
            const float4* T = lds + l * CELLS;
            // 4 independent gathers issued before any dependent VALU
            int ia = cell_index(az2);
            int ib = cell_index(bz2);
            int ic = cell_index(cz2);
            int id = cell_index(dz2);
            float4 ca = T[ia];
            float4 cb = T[ib];
            float4 cc = T[ic];
            float4 cd = T[id];

            float als = fmaf(ca.x, az2, ca.y);
            float ag  = fmaf(ca.z, az2, ca.w);
            float bls = fmaf(cb.x, bz2, cb.y);
            float bg  = fmaf(cb.z, bz2, cb.w);
            float cls = fmaf(cc.x, cz2, cc.y);
            float cg  = fmaf(cc.z, cz2, cc.w);
            float dls = fmaf(cd.x, dz2, cd.y);
            float dg  = fmaf(cd.z, dz2, cd.w);

            float az2n = fmaf(fast_exp2(als), az1, ag);
            float bz2n = fmaf(fast_exp2(bls), bz1, bg);
            float cz2n = fmaf(fast_exp2(cls), cz1, cg);
            float dz2n = fmaf(fast_exp2(dls), dz1, dg);

            az1 = az2; az2 = az2n; ald += als;
            bz1 = bz2; bz2 = bz2n; bld += bls;
            cz1 = cz2; cz2 = cz2n; cld += cls;
            dz1 = dz2; dz2 = dz2n; dld += dls;
        }

        out_z[p0]  = make_float4(az1, az2, bz1, bz2);
        out_ld[p0] = make_float2(ald * LN2F, bld * LN2F);
        if (has1) {
            out_z[p1]  = make_float4(cz1, cz2, dz1, dz2);
            out_ld[p1] = make_float2(cld * LN2F, dld * LN2F);
        }
    }
}

extern "C" void kernel_launch(void* const* d_in, const int* in_sizes, int n_in,
                              void* d_out, int out_size, void* d_ws, size_t ws_size,
                              hipStream_t stream) {
    const int n = in_sizes[0] / 2;
    const int npair = n / 2;             // N = 4194304 is even

    const float4* x       = (const float4*)d_in[0];
    const float*  scale_w = (const float*)d_in[1];
    const float*  scale_b = (const float*)d_in[2];
    const float*  sW1     = (const float*)d_in[3];
    const float*  sb1     = (const float*)d_in[4];
    const float*  sW2     = (const float*)d_in[5];
    const float*  sb2     = (const float*)d_in[6];
    const float*  sW3     = (const float*)d_in[7];
    const float*  sb3     = (const float*)d_in[8];
    const float*  tW1     = (const float*)d_in[9];
    const float*  tb1     = (const float*)d_in[10];
    const float*  tW2     = (const float*)d_in[11];
    const float*  tb2     = (const float*)d_in[12];
    const float*  tW3     = (const float*)d_in[13];
    const float*  tb3     = (const float*)d_in[14];

    float4* out_z  = (float4*)d_out;
    float2* out_ld = (float2*)((float*)d_out + (size_t)2 * n);

    build_tables<<<30, 640, 0, stream>>>(scale_w, scale_b,
        sW1, sb1, sW2, sb2, sW3, sb3,
        tW1, tb1, tW2, tb2, tW3, tb3, (float*)d_ws);

    flow_lut<<<256, 1024, 0, stream>>>(x, (const float4*)d_ws, out_z, out_ld, npair);
}